// Round 5
// baseline (1153.247 us; speedup 1.0000x reference)
//
#include <hip/hip_runtime.h>
#include <hip/hip_bf16.h>

// DILATE loss, fused soft-DTW fwd+bwd.
// Round 5: ONE WAVE PER SAMPLE, 8 rows/lane, zero barriers in the main loops.
// Lane l owns rows 8l..8l+7. At diagonal d each lane computes 8 cells; deps:
//   r>0: own registers (time-renamed, rotation-free via unroll-8 parity)
//   r=0: lane l-1's r=7 history -> 2 shuffles/step fwd, 4/step bwd.
// R slab is lane-private (store fwd / reload bwd, 4-deep ring) -> no barrier
// between phases, just a vmcnt drain. Scaled domain R''=R*(100/ln2).

#define NSEQ 512
#define K2   144.269504088896f      // (1/gamma)*log2(e) = 100/ln2
#define SC   0.006931471805599453f  // ln2/100
#define BIGV 1e10f
#define NEGV -1e30f
#define ALPHA 0.5f

#define STEPS 1024
#define SLABF4 ((size_t)STEPS * 128)   // float4 elements per sample slab

__global__ __launch_bounds__(64) void dilate_wave(
    const float* __restrict__ outp, const float* __restrict__ targ,
    float4* __restrict__ slabAll, float* __restrict__ vals,
    float* __restrict__ svals, int kbase)
{
    const int l = threadIdx.x;              // lane 0..63
    const int k = kbase + blockIdx.x;
    const int base8 = 8 * l;

    __shared__ float o_sh[NSEQ];
    __shared__ float t_sh[NSEQ + 8];

    for (int q = l; q < NSEQ; q += 64) {
        o_sh[q] = outp[(size_t)k * NSEQ + q];
        t_sh[q] = targ[(size_t)k * NSEQ + q];
    }
    if (l < 8) t_sh[NSEQ + l] = 0.f;
    __syncthreads();                        // only barrier (staging)

    float t[9];
    #pragma unroll
    for (int r = 0; r < 9; ++r) t[r] = t_sh[base8 + r];

    float4* __restrict__ sp = slabAll + (size_t)blockIdx.x * SLABF4 + 2 * l;

    // ---------------- forward ----------------
    // P1 = R at diag d-1, P2 = R at diag d-2; new diag-d values overwrite P2.
    float Ra[8], Rb[8], ow[8];
    #pragma unroll
    for (int r = 0; r < 8; ++r) { Ra[r] = BIGV; Rb[r] = BIGV; ow[r] = 0.f; }

    for (int db = 0; db < STEPS; db += 8) {
        #pragma unroll
        for (int u = 0; u < 8; ++u) {
            const int d = db + u;
            float* P1 = (u & 1) ? Rb : Ra;
            float* P2 = (u & 1) ? Ra : Rb;
            const int jt = d - base8;               // j of row r=0
            int ob = jt; ob = ob < 0 ? 0 : (ob > 511 ? 511 : ob);
            ow[u & 7] = o_sh[ob];                   // o[j_0]; cell r uses slot (u-r)&7
            const float sa = __shfl_up(P1[7], 1);   // R[8l-1, j_0]   (diag d-1)
            const float sb = __shfl_up(P2[7], 1);   // R[8l-1, j_0-1] (diag d-2)
            const float a0 = (l == 0) ? BIGV : sa;
            const float b0 = (l == 0) ? ((d == 0) ? 0.f : BIGV) : sb;
            float st[8];
            #pragma unroll
            for (int rr = 0; rr < 8; ++rr) {
                const int r = 7 - rr;               // descending: write P2[r] after reads of P2[r-1] by higher r
                const float a = r ? P1[r - 1] : a0; // R[i-1, j]
                const float b = r ? P2[r - 1] : b0; // R[i-1, j-1]
                const float c = P1[r];              // R[i, j-1]
                const float mn = fminf(fminf(a, b), c);
                const float mx = fmaxf(fmaxf(a, b), c);
                const float md = __builtin_amdgcn_fmed3f(a, b, c);
                const float s = 1.f + __builtin_exp2f(mn - md) + __builtin_exp2f(mn - mx);
                const float sm = mn - __builtin_log2f(s);
                const float orr = ow[(u - r) & 7];  // o[j_r]
                const float dv = t[r] - orr;
                const float val = fmaf(dv * dv, K2, sm);
                const bool act = ((unsigned)(jt - r)) < 512u;
                st[r] = act ? val : NEGV;           // slab copy (NEGV => zero weight in bwd)
                P2[r] = act ? val : BIGV;           // DP carry (BIG => loses softmin)
                if (d == 1022 && r == 7) { if (l == 63) vals[k] = val * SC; }
            }
            const float4 v0 = make_float4(st[0], st[1], st[2], st[3]);
            const float4 v1 = make_float4(st[4], st[5], st[6], st[7]);
            sp[d * 128]     = v0;
            sp[d * 128 + 1] = v1;
        }
    }

    // own-lane store->load ordering for the slab (no cross-lane deps!)
    asm volatile("s_waitcnt vmcnt(0)" ::: "memory");

    // ---------------- backward ----------------
    // EP1/RP1 = diag d+1, EP2/RP2 = diag d+2; new diag-d overwrites P2.
    float Ea[8], Eb[8], Sa[8], Sb[8];
    #pragma unroll
    for (int r = 0; r < 8; ++r) { Ea[r] = 0.f; Eb[r] = 0.f; Sa[r] = NEGV; Sb[r] = NEGV; }

    #pragma unroll
    for (int s = 0; s < 8; ++s) {           // ow[s] = o[1024 - 8l - s]
        int ob = 1024 - base8 - s;
        ob = ob < 0 ? 0 : (ob > 511 ? 511 : ob);
        ow[s] = o_sh[ob];
    }
    float4 ringA[4], ringB[4];
    #pragma unroll
    for (int q = 0; q < 4; ++q) {           // slot q holds step 1023-q
        ringA[q] = sp[(1023 - q) * 128];
        ringB[q] = sp[(1023 - q) * 128 + 1];
    }

    float acc = 0.f;

    for (int db = 1023; db >= 7; db -= 8) {
        #pragma unroll
        for (int u = 0; u < 8; ++u) {
            const int d = db - u;
            float* EP1 = (u & 1) ? Eb : Ea;
            float* EP2 = (u & 1) ? Ea : Eb;
            float* RP1 = (u & 1) ? Sb : Sa;
            float* RP2 = (u & 1) ? Sa : Sb;
            const int slot = u & 3;
            const float4 rc0 = ringA[slot];  // R[8l..8l+3, ·] at diag d
            const float4 rc1 = ringB[slot];  // R[8l+4..8l+7, ·]
            {   // prefetch diag d-4 into the freed slot
                int dp = d - 4; dp = dp < 0 ? 0 : dp;
                ringA[slot] = sp[dp * 128];
                ringB[slot] = sp[dp * 128 + 1];
            }
            const int jt = d - base8;                // j of row r=0
            int obn = jt - 7; obn = obn < 0 ? 0 : (obn > 511 ? 511 : obn);
            const float ocar = ow[u & 7];            // o[j_0 + 1] (loaded 8 steps ago)
            ow[u & 7] = o_sh[obn];                   // o[j_7]; cell r uses slot (u+r+1)&7
            const float sE1 = __shfl_down(EP1[0], 1);  // row 8l+8, diag d+1
            const float sE2 = __shfl_down(EP2[0], 1);  // row 8l+8, diag d+2
            const float sR1 = __shfl_down(RP1[0], 1);
            const float sR2 = __shfl_down(RP2[0], 1);
            const float eA7 = (l == 63) ? 0.f  : sE1;
            const float eB7 = (l == 63) ? 0.f  : sE2;
            const float rA7 = (l == 63) ? NEGV : sR1;
            const float rB7 = (l == 63) ? NEGV : sR2;
            // X[q] = (t[q] - o[j_q + 1])^2 ; XA(r)=X[r+1], XC(r)=X[r]
            float X[9];
            #pragma unroll
            for (int q = 0; q < 9; ++q) {
                const float oq = q ? ow[(u + q) & 7] : ocar;
                const float dvq = t[q] - oq;
                X[q] = dvq * dvq;
            }
            const float rcv[8] = {rc0.x, rc0.y, rc0.z, rc0.w,
                                  rc1.x, rc1.y, rc1.z, rc1.w};
            const float dfb = (float)(16 * l - d);   // (i - j) = 16l + 2r - d
            #pragma unroll
            for (int r = 0; r < 8; ++r) {            // ascending: cell r writes P2[r], reads P2[r+1]
                const float rij = rcv[r];
                const float e1c = (r < 7) ? EP1[r + 1] : eA7;  // E[i+1, j]
                const float r1c = (r < 7) ? RP1[r + 1] : rA7;
                const float e2c = (r < 7) ? EP2[r + 1] : eB7;  // E[i+1, j+1]
                const float r2c = (r < 7) ? RP2[r + 1] : rB7;
                const float eoc = EP1[r];                      // E[i, j+1]
                const float roc = RP1[r];
                const float oj1 = r ? ow[(u + r) & 7] : ocar;  // o[j_r + 1]
                const float dvb = t[r + 1] - oj1;
                const float XB = dvb * dvb;                    // D[i+1, j+1]
                float e = e1c * __builtin_exp2f(fmaf(X[r + 1], -K2, r1c - rij));
                e = fmaf(eoc, __builtin_exp2f(fmaf(X[r], -K2, roc - rij)), e);
                e = fmaf(e2c, __builtin_exp2f(fmaf(XB, -K2, r2c - rij)), e);
                const bool act = ((unsigned)(jt - r)) < 512u;
                float E = act ? e : 0.f;
                if (d == 1022 && r == 7) E = (l == 63) ? 1.f : E;  // seed E[511,511]=1
                const float df = dfb + (float)(2 * r);
                acc = fmaf(E * df, df, acc);
                EP2[r] = E;
                RP2[r] = rij;
            }
        }
    }

    // wave-reduce temporal accumulator
    for (int off = 32; off; off >>= 1) acc += __shfl_down(acc, off);
    if (l == 0) svals[k] = acc;
}

__global__ void finalize_kernel(const float* __restrict__ vals,
                                const float* __restrict__ svals,
                                float* __restrict__ out, int B) {
    int t = threadIdx.x;
    float v = 0.0f, s = 0.0f;
    for (int q = t; q < B; q += 64) { v += vals[q]; s += svals[q]; }
    for (int off = 32; off; off >>= 1) { v += __shfl_down(v, off); s += __shfl_down(s, off); }
    if (t == 0) {
        float loss_shape = v / (float)B;
        float loss_temporal = (s / (float)B) / ((float)NSEQ * (float)NSEQ);
        out[0] = ALPHA * loss_shape + (1.0f - ALPHA) * loss_temporal;
    }
}

extern "C" void kernel_launch(void* const* d_in, const int* in_sizes, int n_in,
                              void* d_out, int out_size, void* d_ws, size_t ws_size,
                              hipStream_t stream) {
    const float* outputs = (const float*)d_in[0];
    const float* targets = (const float*)d_in[1];
    const int B = in_sizes[0] / NSEQ;    // 64

    float* vals  = (float*)d_ws;
    float* svals = vals + 128;
    float4* slab = (float4*)((char*)d_ws + 1024);

    const size_t slab_bytes = SLABF4 * sizeof(float4);   // 2 MiB/sample
    size_t avail = (ws_size > 1024) ? (ws_size - 1024) / slab_bytes : 0;
    int G = (int)((avail < (size_t)B) ? avail : (size_t)B);
    if (G < 1) G = 1;

    for (int kb = 0; kb < B; kb += G) {
        int g = (B - kb < G) ? (B - kb) : G;
        dilate_wave<<<dim3(g), dim3(64), 0, stream>>>(outputs, targets, slab, vals, svals, kb);
    }
    finalize_kernel<<<dim3(1), dim3(64), 0, stream>>>(vals, svals, (float*)d_out, B);
}

// Round 6
// 1118.386 us; speedup vs baseline: 1.0312x; 1.0312x over previous
//
#include <hip/hip_runtime.h>

// DILATE loss, fused soft-DTW fwd+bwd. One wave per sample, 8 rows/lane,
// zero barriers in the main loops.
// Round 6: mask-free DP (padded o, OOB cells compute harmless garbage;
// min(arg,0) clamp keeps weights finite), batched aligned ds_read_b128
// o-window (conflict-free), software-pipelined cross-lane shuffles
// (issued one step ahead), uniform-base slab addressing, diag-child D
// reuse (Q[r] = Pprev[r+1]). Scaled domain R'' = R * (100/ln2).

#define NSEQ 512
#define K2   144.269504088896f      // (1/gamma)*log2(e) = 100/ln2
#define SC   0.006931471805599453f  // ln2/100
#define BIGV 1e10f
#define NEGV -1e30f
#define ALPHA 0.5f
#define SLABF4 ((size_t)1024 * 128)  // float4 per sample slab

typedef float4 f4;

// static float4 component select (c folds after unroll)
#define C4(v, c) ((c)==0 ? (v).x : (c)==1 ? (v).y : (c)==2 ? (v).z : (v).w)
// o-window element s in [0,15]: low = w0,w1  high = w2,w3
#define WEL(s) ((s)<4 ? C4(w0,(s)) : (s)<8 ? C4(w1,(s)-4) : \
                (s)<12 ? C4(w2,(s)-8) : C4(w3,(s)-12))

__global__ __launch_bounds__(64) void dilate_wave(
    const float* __restrict__ outp, const float* __restrict__ targ,
    f4* __restrict__ slabAll, float* __restrict__ vals,
    float* __restrict__ svals, int kbase)
{
    const int l = threadIdx.x;
    const int k = kbase + blockIdx.x;
    const int base8 = 8 * l;
    const bool l63 = (l == 63);

    __shared__ __align__(16) float o_pad[1544];  // o[j] at [511+j], zeros outside
    __shared__ float t_sh[520];

    for (int q = l; q < 1544; q += 64) o_pad[q] = 0.f;
    for (int q = l; q < 520; q += 64) t_sh[q] = 0.f;
    __syncthreads();
    for (int q = l; q < NSEQ; q += 64) {
        o_pad[511 + q] = outp[(size_t)k * NSEQ + q];
        t_sh[q]        = targ[(size_t)k * NSEQ + q];
    }
    __syncthreads();

    float t[9];
    #pragma unroll
    for (int r = 0; r < 9; ++r) t[r] = t_sh[base8 + r];

    f4* __restrict__ slab_k = slabAll + (size_t)blockIdx.x * SLABF4;

    // ================= forward =================
    float Ra[8], Rb[8];
    #pragma unroll
    for (int r = 0; r < 8; ++r) { Ra[r] = BIGV; Rb[r] = BIGV; }

    f4 w0, w1, w2, w3;
    int fofs = 504 - base8;                    // window base (16B aligned)
    {
        const f4* rp = (const f4*)&o_pad[fofs];
        w0 = rp[0]; w1 = rp[1]; w2 = rp[2]; w3 = rp[3];
    }
    float sa = BIGV, sb = BIGV, bl0 = 0.f;     // pipelined boundary; bl0: R[-1,-1]=0 at d=0

    for (int db = 0; db < 1024; db += 8) {
        f4 nf0, nf1;                            // prefetch next group's high half
        {
            const f4* rp = (const f4*)&o_pad[fofs + 16];
            nf0 = rp[0]; nf1 = rp[1];
        }
        #pragma unroll
        for (int u = 0; u < 8; ++u) {           // d = db + u
            float* P1 = (u & 1) ? Rb : Ra;      // diag d-1
            float* P2 = (u & 1) ? Ra : Rb;      // diag d-2 -> overwritten with d
            float nsa = 0.f, nsb = 0.f;
            #pragma unroll
            for (int rr = 0; rr < 8; ++rr) {
                const int r = 7 - rr;           // descending: P2[r-1] still diag d-2
                const float a = r ? P1[r - 1] : (l ? sa : BIGV);   // R[i-1, j]
                const float b = r ? P2[r - 1] : (l ? sb : bl0);    // R[i-1, j-1]
                const float c = P1[r];                              // R[i, j-1]
                const float mn = fminf(fminf(a, b), c);
                const float mx = fmaxf(fmaxf(a, b), c);
                const float md = __builtin_amdgcn_fmed3f(a, b, c);
                const float ssum = 1.f + __builtin_exp2f(mn - md)
                                       + __builtin_exp2f(mn - mx);
                const float dv = t[r] - WEL(7 + u - r);             // o[j_r]
                const float nv = fmaf(dv * dv, K2, mn - __builtin_log2f(ssum));
                P2[r] = nv;
                if (r == 7) {
                    nsa = __shfl_up(nv, 1);      // R[8l-1, j0'] (diag d) for step u+1
                    nsb = __shfl_up(P1[7], 1);   // diag d-1
                    if (u == 6) { if (db == 1016 && l63) vals[k] = nv * SC; }
                }
            }
            sa = nsa; sb = nsb; bl0 = BIGV;
            f4* srow = slab_k + (size_t)(db + u) * 128;   // uniform base
            srow[2 * l]     = make_float4(P2[0], P2[1], P2[2], P2[3]);
            srow[2 * l + 1] = make_float4(P2[4], P2[5], P2[6], P2[7]);
        }
        w0 = w2; w1 = w3; w2 = nf0; w3 = nf1;   // slide window up by 8
        fofs += 8;
    }

    // own-lane store->load ordering for the slab (strictly lane-private)
    asm volatile("s_waitcnt vmcnt(0)" ::: "memory");

    // ================= backward =================
    float Ea[8], Eb[8], Sa[8], Sb[8], PA[9], PB[9];
    #pragma unroll
    for (int r = 0; r < 8; ++r) { Ea[r] = 0.f; Eb[r] = 0.f; Sa[r] = NEGV; Sb[r] = NEGV; }
    #pragma unroll
    for (int q = 0; q < 9; ++q) { PA[q] = 0.f; PB[q] = 0.f; }

    int bofs = 1520 - base8;                    // window base (16B aligned)
    {
        const f4* rp = (const f4*)&o_pad[bofs];
        w0 = rp[0]; w1 = rp[1]; w2 = rp[2]; w3 = rp[3];
    }
    f4 rgA[4], rgB[4];                          // 4-deep slab ring
    #pragma unroll
    for (int s = 0; s < 4; ++s) {
        const f4* lrow = slab_k + (size_t)(1023 - s) * 128;
        rgA[s] = lrow[2 * l]; rgB[s] = lrow[2 * l + 1];
    }
    float sE1 = 0.f, sE2 = 0.f, sR1 = NEGV, sR2 = NEGV;  // pipelined boundary
    float acc = 0.f;

    for (int db = 1023; db >= 7; db -= 8) {
        f4 nf0, nf1;                            // prefetch next group's low half
        {
            int rb = bofs - 8; if (rb < 0) rb = 0;
            const f4* rp = (const f4*)&o_pad[rb];
            nf0 = rp[0]; nf1 = rp[1];
        }
        #pragma unroll
        for (int u = 0; u < 8; ++u) {           // d = db - u
            const int slot = u & 3;
            const f4 rc0 = rgA[slot];           // R rows 8l..8l+3 at diag d
            const f4 rc1 = rgB[slot];           // R rows 8l+4..8l+7
            {                                   // prefetch diag d-4
                int dp = db - u - 4; if (dp < 0) dp = 0;
                const f4* lrow = slab_k + (size_t)dp * 128;
                rgA[slot] = lrow[2 * l]; rgB[slot] = lrow[2 * l + 1];
            }
            float* EP1 = (u & 1) ? Eb : Ea;     // diag d+1
            float* EP2 = (u & 1) ? Ea : Eb;     // diag d+2 -> overwritten with d
            float* RP1 = (u & 1) ? Sb : Sa;
            float* RP2 = (u & 1) ? Sa : Sb;
            float* Pc  = (u & 1) ? PB : PA;     // fresh right/down child D's
            float* Pp  = (u & 1) ? PA : PB;     // previous step's (diag-child D's)
            #pragma unroll
            for (int q = 0; q < 9; ++q) {       // Pc[q] = (t[q] - o[j_q + 1])^2
                const float dq = t[q] - WEL(15 - u - q);
                Pc[q] = dq * dq;
            }
            const float dif0 = (float)(16 * l - db + u);   // i-j at r=0
            float nsE1 = 0.f, nsE2 = 0.f, nsR1 = NEGV, nsR2 = NEGV;
            #pragma unroll
            for (int r = 0; r < 8; ++r) {       // ascending: EP2[r+1] still diag d+2
                const float rij = (r < 4) ? C4(rc0, r) : C4(rc1, r - 4);
                const float eD = (r < 7) ? EP1[r + 1] : (l63 ? 0.f  : sE1);  // E[i+1,j]   d+1
                const float rD = (r < 7) ? RP1[r + 1] : (l63 ? NEGV : sR1);
                const float eX = (r < 7) ? EP2[r + 1] : (l63 ? 0.f  : sE2);  // E[i+1,j+1] d+2
                const float rX = (r < 7) ? RP2[r + 1] : (l63 ? NEGV : sR2);
                const float eR = EP1[r];                                     // E[i,j+1]   d+1
                const float rR = RP1[r];
                const float a1 = fminf(fmaf(Pc[r + 1], -K2, rD - rij), 0.f);
                const float a2 = fminf(fmaf(Pc[r],     -K2, rR - rij), 0.f);
                const float a3 = fminf(fmaf(Pp[r + 1], -K2, rX - rij), 0.f);
                float E = eD * __builtin_exp2f(a1);
                E = fmaf(eR, __builtin_exp2f(a2), E);
                E = fmaf(eX, __builtin_exp2f(a3), E);
                if (u == 1 && r == 7) { if (db == 1023) E = l63 ? 1.f : E; } // seed (511,511)
                const float df = dif0 + (float)(2 * r);
                acc = fmaf(E * df, df, acc);
                EP2[r] = E; RP2[r] = rij;
                if (r == 0) {
                    nsE1 = __shfl_down(E, 1);        // diag d   row 8l+8
                    nsE2 = __shfl_down(EP1[0], 1);   // diag d+1 row 8l+8
                    nsR1 = __shfl_down(rij, 1);
                    nsR2 = __shfl_down(RP1[0], 1);
                }
            }
            sE1 = nsE1; sE2 = nsE2; sR1 = nsR1; sR2 = nsR2;
        }
        w2 = w0; w3 = w1; w0 = nf0; w1 = nf1;   // slide window down by 8
        bofs -= 8;
    }

    // wave-reduce temporal accumulator
    for (int off = 32; off; off >>= 1) acc += __shfl_down(acc, off);
    if (l == 0) svals[k] = acc;
}

__global__ void finalize_kernel(const float* __restrict__ vals,
                                const float* __restrict__ svals,
                                float* __restrict__ out, int B) {
    int t = threadIdx.x;
    float v = 0.0f, s = 0.0f;
    for (int q = t; q < B; q += 64) { v += vals[q]; s += svals[q]; }
    for (int off = 32; off; off >>= 1) { v += __shfl_down(v, off); s += __shfl_down(s, off); }
    if (t == 0) {
        float loss_shape = v / (float)B;
        float loss_temporal = (s / (float)B) / ((float)NSEQ * (float)NSEQ);
        out[0] = ALPHA * loss_shape + (1.0f - ALPHA) * loss_temporal;
    }
}

extern "C" void kernel_launch(void* const* d_in, const int* in_sizes, int n_in,
                              void* d_out, int out_size, void* d_ws, size_t ws_size,
                              hipStream_t stream) {
    const float* outputs = (const float*)d_in[0];
    const float* targets = (const float*)d_in[1];
    const int B = in_sizes[0] / NSEQ;    // 64

    float* vals  = (float*)d_ws;
    float* svals = vals + 128;
    f4*    slab  = (f4*)((char*)d_ws + 1024);

    const size_t slab_bytes = SLABF4 * sizeof(f4);   // 2 MiB/sample
    size_t avail = (ws_size > 1024) ? (ws_size - 1024) / slab_bytes : 0;
    int G = (int)((avail < (size_t)B) ? avail : (size_t)B);
    if (G < 1) G = 1;

    for (int kb = 0; kb < B; kb += G) {
        int g = (B - kb < G) ? (B - kb) : G;
        dilate_wave<<<dim3(g), dim3(64), 0, stream>>>(outputs, targets, slab, vals, svals, kb);
    }
    finalize_kernel<<<dim3(1), dim3(64), 0, stream>>>(vals, svals, (float*)d_out, B);
}

// Round 7
// 725.377 us; speedup vs baseline: 1.5899x; 1.5418x over previous
//
#include <hip/hip_runtime.h>

// DILATE loss via the soft-DTW forward/backward identity:
//   E[i,j] = exp((V - R[i,j] - Rrev[i,j] + D[i,j]) / gamma)
// where Rrev is the forward recursion on index-reversed sequences.
// Round 7: two INDEPENDENT 4-wave lag-pipelined forward passes (dir 0: R,
// dir 1: Rrev) run concurrently as separate blocks; the E/temporal term is
// then a pointwise map-reduce over all B*N^2 cells at HBM rate.
// Scaled domain R'' = R * (100/ln2) so softmin uses raw exp2/log2.

#define NSEQ 512
#define K2   144.269504088896f      // (1/gamma)*log2(e) = 100/ln2
#define SC   0.006931471805599453f  // ln2/100
#define BIGV 1e10f
#define NEGV -1e30f
#define ALPHA 0.5f

#define SLAB ((size_t)1024 * NSEQ)  // floats per sample per direction (diag-major [d][i])

// ---------------- wavefront pass (round-3 proven fwd skeleton) ----------------
// 4 waves, 2 rows/lane (i0 = 128w + 2l), superstep = 64 diagonals, lag-3
// schedule; strip boundary row via LDS column arrays; raw lgkm barrier only.
__global__ __launch_bounds__(256) void sdtw_pass(
    const float* __restrict__ outp, const float* __restrict__ targ,
    float* __restrict__ slabA, float* __restrict__ slabB,
    float* __restrict__ vals, float* __restrict__ vraw, int kbase)
{
    const int tid = threadIdx.x;
    const int w = tid >> 6, l = tid & 63;
    const int i0 = 128 * w + 2 * l;          // lane owns rows i0, i0+1
    const int dir = blockIdx.x & 1;
    const int kk  = blockIdx.x >> 1;
    const int k   = kbase + kk;
    const bool lane0 = (l == 0), lane63 = (l == 63);

    __shared__ float o_pad[644];   // o[j] at [j+1], pads 0
    __shared__ float t_sh[516];
    __shared__ float Rbf[3][644];  // boundary row 128(w+1)-1 by column (col c at [c+1])
    __shared__ float dummyF[644];  // virtual row -1: [0]=0 (R[-1,-1]), else BIG

    for (int q = tid; q < 644; q += 256) { o_pad[q] = 0.f; dummyF[q] = BIGV; }
    for (int q = tid; q < 516; q += 256) t_sh[q] = 0.f;
    __syncthreads();
    if (tid == 0) {
        dummyF[0] = 0.f;                     // virtual R[-1,-1] = 0
        Rbf[0][0] = BIGV; Rbf[1][0] = BIGV; Rbf[2][0] = BIGV;
    }
    for (int q = tid; q < NSEQ; q += 256) {  // dir 1: reversed sequences
        const int src = dir ? (NSEQ - 1 - q) : q;
        o_pad[1 + q] = outp[(size_t)k * NSEQ + src];
        t_sh[q]      = targ[(size_t)k * NSEQ + src];
    }
    __syncthreads();

    const float t0 = t_sh[i0], t1 = t_sh[i0 + 1];
    const float* RbfR = (w == 0) ? dummyF : Rbf[w - 1];
    float*       RbfW = Rbf[w < 3 ? w : 2];          // guarded by (w<3)

    float2* __restrict__ s2 =
        (float2*)((dir ? slabB : slabA) + (size_t)kk * SLAB);

    float rp1_0 = BIGV, rp1_1 = BIGV, rp2_0 = BIGV, rp2_1 = BIGV;
    float rfinal = BIGV;

    for (int ss = 0; ss < 19; ++ss) {
        const int mw = ss - 3 * w;               // wave-local window
        if (0 <= mw && mw < 10) {
            const int tb = (mw + 2 * w) * 64;    // global diag base
            int j0 = tb - i0;
            #pragma unroll 8
            for (int u = 0; u < 64; ++u, ++j0) {
                const int ob = (j0 > 0) ? j0 : 0;
                const float oj  = o_pad[ob + 1];     // o[j0]
                const float ojm = o_pad[ob];         // o[j0-1]
                const float bdA = RbfR[ob + 1];      // R[i0-1, j0]
                const float bdB = RbfR[ob];          // R[i0-1, j0-1]
                const float sA = __shfl_up(rp1_1, 1);
                const float sB = __shfl_up(rp2_1, 1);
                const float a0 = lane0 ? bdA : sA;
                const float b0 = lane0 ? bdB : sB;
                const float c0 = rp1_0;
                // cell r=0: (i0, j0): softmin = mn - log2(1 + 2^(mn-md) + 2^(mn-mx))
                float mn0 = fminf(fminf(a0, b0), c0);
                float mx0 = fmaxf(fmaxf(a0, b0), c0);
                float md0 = __builtin_amdgcn_fmed3f(a0, b0, c0);
                float s0 = 1.0f + __builtin_exp2f(mn0 - md0) + __builtin_exp2f(mn0 - mx0);
                float sm0 = mn0 - __builtin_log2f(s0);
                float dv0 = t0 - oj;
                float r0v = fmaf(dv0 * dv0, K2, sm0);
                // cell r=1: (i0+1, j0-1) — uses only pre-rotation registers
                float mn1 = fminf(fminf(rp1_0, rp2_0), rp1_1);
                float mx1 = fmaxf(fmaxf(rp1_0, rp2_0), rp1_1);
                float md1 = __builtin_amdgcn_fmed3f(rp1_0, rp2_0, rp1_1);
                float s1 = 1.0f + __builtin_exp2f(mn1 - md1) + __builtin_exp2f(mn1 - mx1);
                float sm1 = mn1 - __builtin_log2f(s1);
                float dv1 = t1 - ojm;
                float r1v = fmaf(dv1 * dv1, K2, sm1);
                const bool act0 = ((unsigned)j0 < 512u);
                const bool act1 = ((unsigned)(j0 - 1) < 512u);
                const float r0n = act0 ? r0v : BIGV;
                const float r1n = act1 ? r1v : BIGV;
                rp2_0 = rp1_0; rp1_0 = r0n;
                rp2_1 = rp1_1; rp1_1 = r1n;
                float2 st; st.x = act0 ? r0v : NEGV; st.y = act1 ? r1v : NEGV;
                s2[(size_t)(tb + u) * 256 + 64 * w + l] = st;   // slab[d][i0..i0+1]
                if (lane63 && w < 3 && act1) RbfW[j0] = r1n;    // col j0-1 at [j0]
                if (u == 62 && mw == 9) rfinal = r1v;           // cell (511,511)
            }
        }
        asm volatile("s_waitcnt lgkmcnt(0)\n\ts_barrier" ::: "memory");
    }
    if (w == 3 && lane63 && dir == 0) { vals[k] = rfinal * SC; vraw[k] = rfinal; }
}

// ---------------- pointwise E map-reduce ----------------
// E[i,j] = exp2(Vraw - A[i,j] - B[i,j] + D[i,j]*K2); acc += E*(i-j)^2.
// A = slabA[d][i], B = slabB[1022-d][511-i] (flipped-pass layout).
__global__ __launch_bounds__(256) void ereduce(
    const float* __restrict__ outp, const float* __restrict__ targ,
    const float* __restrict__ slabA, const float* __restrict__ slabB,
    const float* __restrict__ vraw, float* __restrict__ spart, int kbase)
{
    const int tid = threadIdx.x;
    const int sect = blockIdx.x & 7;
    const int kk = blockIdx.x >> 3;
    const int k = kbase + kk;

    __shared__ float t_sh[NSEQ], o_sh[NSEQ];
    __shared__ float red[4];
    for (int q = tid; q < NSEQ; q += 256) {
        t_sh[q] = targ[(size_t)k * NSEQ + q];
        o_sh[q] = outp[(size_t)k * NSEQ + q];
    }
    __syncthreads();

    const float* __restrict__ A  = slabA + (size_t)kk * SLAB;
    const float* __restrict__ Bs = slabB + (size_t)kk * SLAB;
    const float V = vraw[k];
    float acc = 0.f;
    const int dend = (sect == 7) ? 1023 : (sect * 128 + 128);
    for (int d = sect * 128; d < dend; ++d) {
        const int ilo = (d < NSEQ) ? 0 : (d - NSEQ + 1);
        const int ihi = (d < NSEQ) ? d : (NSEQ - 1);
        for (int i = ilo + tid; i <= ihi; i += 256) {
            const float a = A[(size_t)d * NSEQ + i];
            const float b = Bs[(size_t)(1022 - d) * NSEQ + (NSEQ - 1 - i)];
            const float dv = t_sh[i] - o_sh[d - i];
            const float arg = fmaf(dv * dv, K2, V - a - b);
            const float E = __builtin_exp2f(arg);      // in [0, 1+eps]
            const float df = (float)(2 * i - d);       // i - j
            acc = fmaf(E * df, df, acc);
        }
    }
    for (int off = 32; off; off >>= 1) acc += __shfl_down(acc, off);
    if ((tid & 63) == 0) red[tid >> 6] = acc;
    __syncthreads();
    if (tid == 0) spart[k * 8 + sect] = red[0] + red[1] + red[2] + red[3];
}

__global__ void finalize_kernel(const float* __restrict__ vals,
                                const float* __restrict__ spart,
                                float* __restrict__ out, int B) {
    int t = threadIdx.x;    // 64 threads
    float v = 0.0f, s = 0.0f;
    for (int q = t; q < B; q += 64) v += vals[q];
    for (int q = t; q < 8 * B; q += 64) s += spart[q];
    for (int off = 32; off; off >>= 1) { v += __shfl_down(v, off); s += __shfl_down(s, off); }
    if (t == 0) {
        float loss_shape = v / (float)B;
        float loss_temporal = (s / (float)B) / ((float)NSEQ * (float)NSEQ);
        out[0] = ALPHA * loss_shape + (1.0f - ALPHA) * loss_temporal;
    }
}

extern "C" void kernel_launch(void* const* d_in, const int* in_sizes, int n_in,
                              void* d_out, int out_size, void* d_ws, size_t ws_size,
                              hipStream_t stream) {
    const float* outputs = (const float*)d_in[0];
    const float* targets = (const float*)d_in[1];
    const int B = in_sizes[0] / NSEQ;    // 64

    // ws: [0,256B) vals, [256,512B) vraw, [512,2560B) spart, [4096, ...) slabs
    float* vals  = (float*)d_ws;
    float* vraw  = vals + 64;
    float* spart = vals + 128;
    float* slabs = (float*)((char*)d_ws + 4096);

    const size_t per_sample = 2 * SLAB * sizeof(float);   // 4 MiB (A+B slabs)
    size_t avail = (ws_size > 4096) ? (ws_size - 4096) / per_sample : 0;
    int G = (int)((avail < (size_t)B) ? avail : (size_t)B);
    if (G < 1) G = 1;
    float* slabA = slabs;
    float* slabB = slabs + (size_t)G * SLAB;

    for (int kb = 0; kb < B; kb += G) {
        int g = (B - kb < G) ? (B - kb) : G;
        sdtw_pass<<<dim3(2 * g), dim3(256), 0, stream>>>(
            outputs, targets, slabA, slabB, vals, vraw, kb);
        ereduce<<<dim3(8 * g), dim3(256), 0, stream>>>(
            outputs, targets, slabA, slabB, vraw, spart, kb);
    }
    finalize_kernel<<<dim3(1), dim3(64), 0, stream>>>(vals, spart, (float*)d_out, B);
}

// Round 8
// 419.213 us; speedup vs baseline: 2.7510x; 1.7303x over previous
//
#include <hip/hip_runtime.h>

// DILATE loss via the soft-DTW forward/backward identity:
//   E[i,j] = exp((V - R[i,j] - Rrev[i,j] + D[i,j]) / gamma)
// where Rrev is the forward recursion on index-reversed sequences.
// Round 8: slabs store ONLY valid cells, packed per-diagonal:
//   off(d) = d(d+1)/2                 for d < 512
//   off(d) = N^2 - (1023-d)(1024-d)/2 for d >= 512
//   cell (i,j) at off(d) + i - max(0, d-511)
// -> 1 MiB per sample per direction, 128 MiB total: whole batch fits one
// chunk (no serialized re-runs of the latency-bound wavefront pass).
// Scaled domain R'' = R * (100/ln2) so softmin uses raw exp2/log2.

#define NSEQ 512
#define K2   144.269504088896f      // (1/gamma)*log2(e) = 100/ln2
#define SC   0.006931471805599453f  // ln2/100
#define BIGV 1e10f
#define ALPHA 0.5f

#define PACKN 262144                // N^2 floats per sample per direction

__device__ __forceinline__ int diag_off(int d) {
    if (d < 512) return (d * (d + 1)) >> 1;
    const int m = 1023 - d;
    return PACKN - ((m * (m + 1)) >> 1);
}

// ---------------- wavefront pass (round-3 proven fwd skeleton) ----------------
// 4 waves, 2 rows/lane (i0 = 128w + 2l), superstep = 64 diagonals, lag-3
// schedule; strip boundary row via LDS column arrays; raw lgkm barrier only.
__global__ __launch_bounds__(256) void sdtw_pass(
    const float* __restrict__ outp, const float* __restrict__ targ,
    float* __restrict__ slabA, float* __restrict__ slabB,
    float* __restrict__ vals, float* __restrict__ vraw, int kbase)
{
    const int tid = threadIdx.x;
    const int w = tid >> 6, l = tid & 63;
    const int i0 = 128 * w + 2 * l;          // lane owns rows i0, i0+1
    const int dir = blockIdx.x & 1;
    const int kk  = blockIdx.x >> 1;
    const int k   = kbase + kk;
    const bool lane0 = (l == 0), lane63 = (l == 63);

    __shared__ float o_pad[644];   // o[j] at [j+1], pads 0
    __shared__ float t_sh[516];
    __shared__ float Rbf[3][644];  // boundary row 128(w+1)-1 by column (col c at [c+1])
    __shared__ float dummyF[644];  // virtual row -1: [0]=0 (R[-1,-1]), else BIG

    for (int q = tid; q < 644; q += 256) { o_pad[q] = 0.f; dummyF[q] = BIGV; }
    for (int q = tid; q < 516; q += 256) t_sh[q] = 0.f;
    __syncthreads();
    if (tid == 0) {
        dummyF[0] = 0.f;                     // virtual R[-1,-1] = 0
        Rbf[0][0] = BIGV; Rbf[1][0] = BIGV; Rbf[2][0] = BIGV;
    }
    for (int q = tid; q < NSEQ; q += 256) {  // dir 1: reversed sequences
        const int src = dir ? (NSEQ - 1 - q) : q;
        o_pad[1 + q] = outp[(size_t)k * NSEQ + src];
        t_sh[q]      = targ[(size_t)k * NSEQ + src];
    }
    __syncthreads();

    const float t0 = t_sh[i0], t1 = t_sh[i0 + 1];
    const float* RbfR = (w == 0) ? dummyF : Rbf[w - 1];
    float*       RbfW = Rbf[w < 3 ? w : 2];          // guarded by (w<3)

    float* __restrict__ sp = (dir ? slabB : slabA) + (size_t)kk * PACKN;

    float rp1_0 = BIGV, rp1_1 = BIGV, rp2_0 = BIGV, rp2_1 = BIGV;
    float rfinal = BIGV;

    for (int ss = 0; ss < 19; ++ss) {
        const int mw = ss - 3 * w;               // wave-local window
        if (0 <= mw && mw < 10) {
            const int tb = (mw + 2 * w) * 64;    // global diag base
            int j0 = tb - i0;
            #pragma unroll 8
            for (int u = 0; u < 64; ++u, ++j0) {
                const int ob = (j0 > 0) ? j0 : 0;
                const float oj  = o_pad[ob + 1];     // o[j0]
                const float ojm = o_pad[ob];         // o[j0-1]
                const float bdA = RbfR[ob + 1];      // R[i0-1, j0]
                const float bdB = RbfR[ob];          // R[i0-1, j0-1]
                const float sA = __shfl_up(rp1_1, 1);
                const float sB = __shfl_up(rp2_1, 1);
                const float a0 = lane0 ? bdA : sA;
                const float b0 = lane0 ? bdB : sB;
                const float c0 = rp1_0;
                // cell r=0: (i0, j0): softmin = mn - log2(1 + 2^(mn-md) + 2^(mn-mx))
                float mn0 = fminf(fminf(a0, b0), c0);
                float mx0 = fmaxf(fmaxf(a0, b0), c0);
                float md0 = __builtin_amdgcn_fmed3f(a0, b0, c0);
                float s0 = 1.0f + __builtin_exp2f(mn0 - md0) + __builtin_exp2f(mn0 - mx0);
                float sm0 = mn0 - __builtin_log2f(s0);
                float dv0 = t0 - oj;
                float r0v = fmaf(dv0 * dv0, K2, sm0);
                // cell r=1: (i0+1, j0-1) — uses only pre-rotation registers
                float mn1 = fminf(fminf(rp1_0, rp2_0), rp1_1);
                float mx1 = fmaxf(fmaxf(rp1_0, rp2_0), rp1_1);
                float md1 = __builtin_amdgcn_fmed3f(rp1_0, rp2_0, rp1_1);
                float s1 = 1.0f + __builtin_exp2f(mn1 - md1) + __builtin_exp2f(mn1 - mx1);
                float sm1 = mn1 - __builtin_log2f(s1);
                float dv1 = t1 - ojm;
                float r1v = fmaf(dv1 * dv1, K2, sm1);
                const bool act0 = ((unsigned)j0 < 512u);
                const bool act1 = ((unsigned)(j0 - 1) < 512u);
                const float r0n = act0 ? r0v : BIGV;
                const float r1n = act1 ? r1v : BIGV;
                rp2_0 = rp1_0; rp1_0 = r0n;
                rp2_1 = rp1_1; rp1_1 = r1n;
                // packed store: only valid cells
                const int d = tb + u;
                const int ilo = (d > 511) ? (d - 511) : 0;
                const int basei = diag_off(d) - ilo;
                if (act0) sp[basei + i0]     = r0v;
                if (act1) sp[basei + i0 + 1] = r1v;
                if (lane63 && w < 3 && act1) RbfW[j0] = r1n;    // col j0-1 at [j0]
                if (u == 62 && mw == 9) rfinal = r1v;           // cell (511,511)
            }
        }
        asm volatile("s_waitcnt lgkmcnt(0)\n\ts_barrier" ::: "memory");
    }
    if (w == 3 && lane63 && dir == 0) { vals[k] = rfinal * SC; vraw[k] = rfinal; }
}

// ---------------- pointwise E map-reduce ----------------
// E[i,j] = exp2(Vraw - A[i,j] - B[i',j'] + D[i,j]*K2); acc += E*(i-j)^2,
// with (i',j') = (511-i, 511-j) in the reverse pass's packed layout.
__global__ __launch_bounds__(256) void ereduce(
    const float* __restrict__ outp, const float* __restrict__ targ,
    const float* __restrict__ slabA, const float* __restrict__ slabB,
    const float* __restrict__ vraw, float* __restrict__ spart, int kbase)
{
    const int tid = threadIdx.x;
    const int sect = blockIdx.x & 7;
    const int kk = blockIdx.x >> 3;
    const int k = kbase + kk;

    __shared__ float t_sh[NSEQ], o_sh[NSEQ];
    __shared__ float red[4];
    for (int q = tid; q < NSEQ; q += 256) {
        t_sh[q] = targ[(size_t)k * NSEQ + q];
        o_sh[q] = outp[(size_t)k * NSEQ + q];
    }
    __syncthreads();

    const float* __restrict__ A  = slabA + (size_t)kk * PACKN;
    const float* __restrict__ Bs = slabB + (size_t)kk * PACKN;
    const float V = vraw[k];
    float acc = 0.f;
    const int dend = (sect == 7) ? 1023 : (sect * 128 + 128);
    for (int d = sect * 128; d < dend; ++d) {
        const int ilo = (d > 511) ? (d - 511) : 0;
        const int ihi = (d < 512) ? d : 511;
        const int dp  = 1022 - d;                       // reverse-pass diagonal
        const int iloB = (dp > 511) ? (dp - 511) : 0;   // = max(0, 511-d)
        const int baseA = diag_off(d) - ilo;
        const int baseB = diag_off(dp) + 511 - iloB;    // idxB = baseB - i
        for (int i = ilo + tid; i <= ihi; i += 256) {
            const float a = A[baseA + i];
            const float b = Bs[baseB - i];
            const float dv = t_sh[i] - o_sh[d - i];
            const float arg = fmaf(dv * dv, K2, V - a - b);
            const float E = __builtin_exp2f(arg);      // in [0, 1+eps]
            const float df = (float)(2 * i - d);       // i - j
            acc = fmaf(E * df, df, acc);
        }
    }
    for (int off = 32; off; off >>= 1) acc += __shfl_down(acc, off);
    if ((tid & 63) == 0) red[tid >> 6] = acc;
    __syncthreads();
    if (tid == 0) spart[k * 8 + sect] = red[0] + red[1] + red[2] + red[3];
}

__global__ void finalize_kernel(const float* __restrict__ vals,
                                const float* __restrict__ spart,
                                float* __restrict__ out, int B) {
    int t = threadIdx.x;    // 64 threads
    float v = 0.0f, s = 0.0f;
    for (int q = t; q < B; q += 64) v += vals[q];
    for (int q = t; q < 8 * B; q += 64) s += spart[q];
    for (int off = 32; off; off >>= 1) { v += __shfl_down(v, off); s += __shfl_down(s, off); }
    if (t == 0) {
        float loss_shape = v / (float)B;
        float loss_temporal = (s / (float)B) / ((float)NSEQ * (float)NSEQ);
        out[0] = ALPHA * loss_shape + (1.0f - ALPHA) * loss_temporal;
    }
}

extern "C" void kernel_launch(void* const* d_in, const int* in_sizes, int n_in,
                              void* d_out, int out_size, void* d_ws, size_t ws_size,
                              hipStream_t stream) {
    const float* outputs = (const float*)d_in[0];
    const float* targets = (const float*)d_in[1];
    const int B = in_sizes[0] / NSEQ;    // 64

    // ws: [0,256B) vals, [256,512B) vraw, [512,2560B) spart, [4096, ...) slabs
    float* vals  = (float*)d_ws;
    float* vraw  = vals + 64;
    float* spart = vals + 128;
    float* slabs = (float*)((char*)d_ws + 4096);

    const size_t per_sample = 2 * (size_t)PACKN * sizeof(float);   // 2 MiB (A+B)
    size_t avail = (ws_size > 4096) ? (ws_size - 4096) / per_sample : 0;
    int G = (int)((avail < (size_t)B) ? avail : (size_t)B);
    if (G < 1) G = 1;
    float* slabA = slabs;
    float* slabB = slabs + (size_t)G * PACKN;

    for (int kb = 0; kb < B; kb += G) {
        int g = (B - kb < G) ? (B - kb) : G;
        sdtw_pass<<<dim3(2 * g), dim3(256), 0, stream>>>(
            outputs, targets, slabA, slabB, vals, vraw, kb);
        ereduce<<<dim3(8 * g), dim3(256), 0, stream>>>(
            outputs, targets, slabA, slabB, vraw, spart, kb);
    }
    finalize_kernel<<<dim3(1), dim3(64), 0, stream>>>(vals, spart, (float*)d_out, B);
}